// Round 5
// baseline (784.779 us; speedup 1.0000x reference)
//
#include <hip/hip_runtime.h>

#define NC   16      // channels
#define NP   48      // perception channels = 3*NC
#define NH   128     // hidden
#define HDIM 256
#define WDIM 256
#define HW   (HDIM*WDIM)

#define PSTR 48      // sP row stride (shorts) = exactly NP (96 B/row)
#define HSTR 136     // H row stride (shorts)

typedef __attribute__((ext_vector_type(8))) short short8;  // 8 bf16 = 1 MFMA operand
typedef __attribute__((ext_vector_type(4))) float f32x4;   // MFMA accumulator / 16B ld
typedef __attribute__((ext_vector_type(4))) int   int4v;   // 16B LDS op
typedef __attribute__((ext_vector_type(2))) int   int2v;   // 8B LDS op

__device__ __forceinline__ unsigned cvt_pk(float lo, float hi) {
    unsigned r;
    asm("v_cvt_pk_bf16_f32 %0, %1, %2" : "=v"(r) : "v"(lo), "v"(hi));
    return r;
}
__device__ __forceinline__ short f2bf(float f) {
    unsigned u = __float_as_uint(f);
    u += 0x7FFFu + ((u >> 16) & 1u);   // RNE
    return (short)(u >> 16);
}

// sP accessor with XOR swizzle: chunk-owned writes have 384B lane stride
// (32-way bank conflict unswizzled); byte ^= ((px>>2)&15)<<3 spreads the
// 16 l&15 groups over 16 banks (writes ~2-way, A-frag reads conflict-free).
// All sP data accesses go through this (b64 granularity keeps XOR closed).
__device__ __forceinline__ int2v* spb(short* sP, int px, int off) {
    int byte = px * 96 + off;
    byte ^= ((px >> 2) & 15) << 3;
    return (int2v*)((char*)sP + byte);
}
__device__ __forceinline__ short8 ld_sp16(short* sP, int px, int off) {
    int2v lo = *spb(sP, px, off);
    int2v hi = *spb(sP, px, off + 8);
    union { int4v i; short8 s; } u;
    int4v c = {lo[0], lo[1], hi[0], hi[1]};
    u.i = c;
    return u.s;
}

__global__ __launch_bounds__(256, 4) void nca_mfma_kernel(
    const float* __restrict__ grid,
    const float* __restrict__ noise,
    const float* __restrict__ w1,
    const float* __restrict__ b1,
    const float* __restrict__ w2,
    const float* __restrict__ b2,
    float* __restrict__ out)
{
    // w1 in MFMA-B-fragment layout; read ONCE into registers after the barrier
    __shared__ short sW1F[8 * 768];          // 12288 B
    // sP [256 px][48] (swizzled); per-wave H overlays own rows 16+ in phase 4
    __shared__ short sP[HDIM * PSTR];        // 24576 B  (total 36864 -> 4 blocks/CU)

    const int tid  = threadIdx.x;
    // XCD band swizzle (kept: FETCH 393->244 MB confirmed)
    const int id   = blockIdx.x;
    const int kk   = id >> 3;
    const int b    = kk >> 5;
    const int y    = (id & 7) * 32 + (kk & 31);

    const int wv   = tid >> 6;
    const int lane = tid & 63;
    const int q    = lane >> 4;
    const int l15  = lane & 15;

    // ---------- Phase 0: stage w1 to LDS in fragment layout ----------
    {
        const int o = tid >> 1, half = tid & 1;   // 2 threads per w1 row
        const float* src = w1 + o * NP + 24 * half;
        const int n = o >> 4, r15 = o & 15;
        #pragma unroll
        for (int g = 0; g < 3; ++g) {
            const int k0 = 24 * half + 8 * g;
            const int tt = k0 >> 5, qq = (k0 & 31) >> 3;
            unsigned u0 = cvt_pk(src[8*g+0], src[8*g+1]);
            unsigned u1 = cvt_pk(src[8*g+2], src[8*g+3]);
            unsigned u2 = cvt_pk(src[8*g+4], src[8*g+5]);
            unsigned u3 = cvt_pk(src[8*g+6], src[8*g+7]);
            int4v v = {(int)u0, (int)u1, (int)u2, (int)u3};
            *(int4v*)&sW1F[n*768 + (tt ? 512 : 0) + (qq*16 + r15)*8] = v;
        }
    }

    // ---------- Phase 1: stencil fully in registers ----------
    // wave wv owns channels 4wv..4wv+3; lane owns pixel chunk 4*lane..4*lane+3.
    // Per (ch,row): 1 coalesced float4 + 2 scalar edge loads (L1-hot). No LDS reads.
    {
        const bool zT = (y == 0), zB = (y == 255);
        const size_t rT = (size_t)(zT ? y : y - 1) * WDIM;
        const size_t rM = (size_t)y * WDIM;
        const size_t rB = (size_t)(zB ? y : y + 1) * WDIM;
        const float* cbase = grid + (size_t)b * NC * HW + (size_t)(4 * wv) * HW;
        const int xel = lane ? 4*lane - 1 : 0;           // clamped; value zeroed below
        const int xer = (lane < 63) ? 4*lane + 4 : 255;

        unsigned d[4][6];    // 6 packed u32 per pixel (12 bf16 = this wave's 4 ch)
        float carry[4];
        #pragma unroll
        for (int c2 = 0; c2 < 4; ++c2) {
            const float* pc = cbase + (size_t)c2 * HW;
            f32x4 vT = *(const f32x4*)&pc[rT + 4*lane];
            f32x4 vM = *(const f32x4*)&pc[rM + 4*lane];
            f32x4 vB = *(const f32x4*)&pc[rB + 4*lane];
            float eTl = pc[rT + xel], eMl = pc[rM + xel], eBl = pc[rB + xel];
            float eTr = pc[rT + xer], eMr = pc[rM + xer], eBr = pc[rB + xer];
            if (zT) { f32x4 z = {0,0,0,0}; vT = z; eTl = 0.f; eTr = 0.f; }  // wave-uniform
            if (zB) { f32x4 z = {0,0,0,0}; vB = z; eBl = 0.f; eBr = 0.f; }
            if (lane == 0)  { eTl = 0.f; eMl = 0.f; eBl = 0.f; }
            if (lane == 63) { eTr = 0.f; eMr = 0.f; eBr = 0.f; }
            #pragma unroll
            for (int i = 0; i < 4; ++i) {
                const float tl = i ? vT[i-1] : eTl;
                const float tr = (i < 3) ? vT[i+1] : eTr;
                const float ml = i ? vM[i-1] : eMl;
                const float mr = (i < 3) ? vM[i+1] : eMr;
                const float bl = i ? vB[i-1] : eBl;
                const float br = (i < 3) ? vB[i+1] : eBr;
                const float p0 = vM[i];
                const float p1 = (tl + tr + 2.f*ml - 2.f*mr + bl - br) * 0.125f;
                const float p2 = (tl + 2.f*vT[i] + tr - bl - 2.f*vB[i] - br) * 0.125f;
                if (c2 == 0)      { d[i][0] = cvt_pk(p0, p1);       carry[i] = p2; }
                else if (c2 == 1) { d[i][1] = cvt_pk(carry[i], p0); d[i][2] = cvt_pk(p1, p2); }
                else if (c2 == 2) { d[i][3] = cvt_pk(p0, p1);       carry[i] = p2; }
                else              { d[i][4] = cvt_pk(carry[i], p0); d[i][5] = cvt_pk(p1, p2); }
            }
        }
        // flush: 12 swizzled b64 writes (3 per pixel) at short-offset 12*wv
        #pragma unroll
        for (int i = 0; i < 4; ++i) {
            const int px = 4*lane + i;
            int2v v0 = {(int)d[i][0], (int)d[i][1]};
            int2v v1 = {(int)d[i][2], (int)d[i][3]};
            int2v v2 = {(int)d[i][4], (int)d[i][5]};
            *spb(sP, px, 24*wv + 0)  = v0;
            *spb(sP, px, 24*wv + 8)  = v1;
            *spb(sP, px, 24*wv + 16) = v2;
        }
    }
    __syncthreads();   // the ONLY barrier: covers sW1F staging + all sP writes

    // ---------- Phase 3: fragments to registers ----------
    short8 w1f0[8], w1f1[8];
    #pragma unroll
    for (int n = 0; n < 8; ++n) {
        w1f0[n] = *(const short8*)&sW1F[n*768 + lane*8];
        short8 z = {}; w1f1[n] = z;
        if (lane < 32) w1f1[n] = *(const short8*)&sW1F[n*768 + 512 + lane*8];
    }
    // w2 B-frags from global (permuted o-space: o' = a*8+j' <-> o = j'*16+a, a=4t+q)
    short8 w2f[4];
    #pragma unroll
    for (int t = 0; t < 4; ++t) {
        short8 v;
        #pragma unroll
        for (int jj = 0; jj < 8; ++jj) v[jj] = f2bf(w2[l15 * NH + jj*16 + 4*t + q]);
        w2f[t] = v;
    }
    float b1v[8];
    #pragma unroll
    for (int n = 0; n < 8; ++n) b1v[n] = b1[16*n + l15];
    const float b2v = b2[l15];

    // ---------- Phase 4: MFMA MLP over this wave's 4 pixel-tiles ----------
    // prefetch A-frags for mt=1..3 (their sP rows get overlaid by H below)
    short8 aF0[3], aF1[3];
    #pragma unroll
    for (int m = 1; m < 4; ++m) {
        const int px = (wv*4 + m)*16 + l15;
        aF0[m-1] = ld_sp16(sP, px, 16*q);
        short8 a1 = {};
        if (q < 2) a1 = ld_sp16(sP, px, 64 + 16*q);   // k=32..47 real; q>=2 -> zero
        aF1[m-1] = a1;
    }
    // H overlays own-wave sP rows 16.. (4352 B needed, 4608 B available)
    short* Hb = &sP[(wv*64 + 16) * PSTR];

    #pragma unroll
    for (int mt = 0; mt < 4; ++mt) {
        short8 a0, a1;
        if (mt == 0) {       // rows 0..15 of own span are never overlaid: read JIT
            const int px = wv*64 + l15;
            a0 = ld_sp16(sP, px, 16*q);
            short8 z = {}; a1 = z;
            if (q < 2) a1 = ld_sp16(sP, px, 64 + 16*q);
        } else { a0 = aF0[mt-1]; a1 = aF1[mt-1]; }

        f32x4 acc[8];
        #pragma unroll
        for (int n = 0; n < 8; ++n) { f32x4 t4 = {b1v[n], b1v[n], b1v[n], b1v[n]}; acc[n] = t4; }
        #pragma unroll
        for (int n = 0; n < 8; ++n)
            acc[n] = __builtin_amdgcn_mfma_f32_16x16x32_bf16(a0, w1f0[n], acc[n], 0, 0, 0);
        #pragma unroll
        for (int n = 0; n < 8; ++n)
            acc[n] = __builtin_amdgcn_mfma_f32_16x16x32_bf16(a1, w1f1[n], acc[n], 0, 0, 0);

        // relu -> bf16 -> H' [m=q*4+r][o'=l15*8+n] (one b128 per r)
        #pragma unroll
        for (int rr = 0; rr < 4; ++rr) {
            unsigned h0 = cvt_pk(fmaxf(acc[0][rr], 0.f), fmaxf(acc[1][rr], 0.f));
            unsigned h1 = cvt_pk(fmaxf(acc[2][rr], 0.f), fmaxf(acc[3][rr], 0.f));
            unsigned h2 = cvt_pk(fmaxf(acc[4][rr], 0.f), fmaxf(acc[5][rr], 0.f));
            unsigned h3 = cvt_pk(fmaxf(acc[6][rr], 0.f), fmaxf(acc[7][rr], 0.f));
            int4v v = {(int)h0, (int)h1, (int)h2, (int)h3};
            *(int4v*)&Hb[(q*4 + rr) * HSTR + l15 * 8] = v;
        }
        // GEMM2: A[m=l15][k=o'=32t+8q+j] from H', B = w2f (same permutation)
        f32x4 acc2 = {b2v, b2v, b2v, b2v};
        #pragma unroll
        for (int t = 0; t < 4; ++t) {
            const short8 af = *(const short8*)&Hb[l15 * HSTR + 32*t + 8*q];
            acc2 = __builtin_amdgcn_mfma_f32_16x16x32_bf16(af, w2f[t], acc2, 0, 0, 0);
        }
        // Epilogue straight from C-layout: lane = (channel j=l15, pixels px0+4q..+3)
        const int px0 = (wv*4 + mt) * 16;
        const int px  = px0 + 4*q;
        const size_t gi = (size_t)b * NC * HW + (size_t)l15 * HW + (size_t)y * WDIM + px;
        const float4 g  = *(const float4*)&grid[gi];   // L2-hot (same XCD as phase 1)
        const float4 nz = *(const float4*)&noise[(size_t)b * HW + (size_t)y * WDIM + px];
        float4 o;
        o.x = fminf(fmaxf(g.x + acc2[0] * (nz.x < 0.5f ? 1.f : 0.f), -2.f), 2.f);
        o.y = fminf(fmaxf(g.y + acc2[1] * (nz.y < 0.5f ? 1.f : 0.f), -2.f), 2.f);
        o.z = fminf(fmaxf(g.z + acc2[2] * (nz.z < 0.5f ? 1.f : 0.f), -2.f), 2.f);
        o.w = fminf(fmaxf(g.w + acc2[3] * (nz.w < 0.5f ? 1.f : 0.f), -2.f), 2.f);
        *(float4*)&out[gi] = o;   // plain store (nt refuted in r4)
    }
}

extern "C" void kernel_launch(void* const* d_in, const int* in_sizes, int n_in,
                              void* d_out, int out_size, void* d_ws, size_t ws_size,
                              hipStream_t stream) {
    const float* grid  = (const float*)d_in[0];
    const float* noise = (const float*)d_in[1];
    const float* w1    = (const float*)d_in[2];
    const float* b1    = (const float*)d_in[3];
    const float* w2    = (const float*)d_in[4];
    const float* b2    = (const float*)d_in[5];
    float* out = (float*)d_out;

    dim3 g(32 * 256);   // one block per (batch, row), XCD-banded inside the kernel
    nca_mfma_kernel<<<g, 256, 0, stream>>>(grid, noise, w1, b1, w2, b2, out);
}

// Round 6
// 763.188 us; speedup vs baseline: 1.0283x; 1.0283x over previous
//
#include <hip/hip_runtime.h>

#define NC   16      // channels
#define NP   48      // perception channels = 3*NC
#define NH   128     // hidden
#define HDIM 256
#define WDIM 256
#define HW   (HDIM*WDIM)

#define PSTR 48      // sP row stride (shorts) = exactly NP (96 B/row)
#define HSTR 136     // H row stride (shorts)

typedef __attribute__((ext_vector_type(8))) short short8;  // 8 bf16 = 1 MFMA operand
typedef __attribute__((ext_vector_type(4))) float f32x4;   // MFMA accumulator / 16B ld
typedef __attribute__((ext_vector_type(4))) int   int4v;   // 16B LDS op
typedef __attribute__((ext_vector_type(2))) int   int2v;   // 8B LDS op

__device__ __forceinline__ unsigned cvt_pk(float lo, float hi) {
    unsigned r;
    asm("v_cvt_pk_bf16_f32 %0, %1, %2" : "=v"(r) : "v"(lo), "v"(hi));
    return r;
}
__device__ __forceinline__ short f2bf(float f) {
    unsigned u = __float_as_uint(f);
    u += 0x7FFFu + ((u >> 16) & 1u);   // RNE
    return (short)(u >> 16);
}

// sP accessor with XOR swizzle (verified correct in r5): XOR of byte-addr bits
// 3..6 stays within each 128B block -> always in-bounds; spreads the 384B-stride
// chunk-owned writes across banks. All sP data accesses use the same 8B blocks.
__device__ __forceinline__ int2v* spb(short* sP, int px, int off) {
    int byte = px * 96 + off;
    byte ^= ((px >> 2) & 15) << 3;
    return (int2v*)((char*)sP + byte);
}
__device__ __forceinline__ int* spb32(short* sP, int px, int off) {
    int byte = px * 96 + off;
    byte ^= ((px >> 2) & 15) << 3;
    return (int*)((char*)sP + byte);
}
__device__ __forceinline__ short8 ld_sp16(short* sP, int px, int off) {
    int2v lo = *spb(sP, px, off);
    int2v hi = *spb(sP, px, off + 8);
    union { int4v i; short8 s; } u;
    int4v c = {lo[0], lo[1], hi[0], hi[1]};
    u.i = c;
    return u.s;
}

__global__ __launch_bounds__(256, 4) void nca_mfma_kernel(
    const float* __restrict__ grid,
    const float* __restrict__ noise,
    const float* __restrict__ w1,
    const float* __restrict__ b1,
    const float* __restrict__ w2,
    const float* __restrict__ b2,
    float* __restrict__ out)
{
    // w1 in MFMA-B-fragment layout; read ONCE into registers after the barrier
    __shared__ short sW1F[8 * 768];          // 12288 B
    // sP [256 px][48] (swizzled); per-wave H overlays own rows 16+ in phase 4
    __shared__ short sP[HDIM * PSTR];        // 24576 B  (total 36864 -> 4 blocks/CU)

    const int tid  = threadIdx.x;
    // XCD band swizzle (FETCH 393->244 MB confirmed in r4)
    const int id   = blockIdx.x;
    const int kk   = id >> 3;
    const int b    = kk >> 5;
    const int y    = (id & 7) * 32 + (kk & 31);

    const int wv   = tid >> 6;
    const int lane = tid & 63;
    const int q    = lane >> 4;
    const int l15  = lane & 15;

    // ---------- Phase 0: stage w1 to LDS in fragment layout ----------
    {
        const int o = tid >> 1, half = tid & 1;   // 2 threads per w1 row
        const float* src = w1 + o * NP + 24 * half;
        const int n = o >> 4, r15 = o & 15;
        #pragma unroll
        for (int g = 0; g < 3; ++g) {
            const int k0 = 24 * half + 8 * g;
            const int tt = k0 >> 5, qq = (k0 & 31) >> 3;
            unsigned u0 = cvt_pk(src[8*g+0], src[8*g+1]);
            unsigned u1 = cvt_pk(src[8*g+2], src[8*g+3]);
            unsigned u2 = cvt_pk(src[8*g+4], src[8*g+5]);
            unsigned u3 = cvt_pk(src[8*g+6], src[8*g+7]);
            int4v v = {(int)u0, (int)u1, (int)u2, (int)u3};
            *(int4v*)&sW1F[n*768 + (tt ? 512 : 0) + (qq*16 + r15)*8] = v;
        }
    }

    // ---------- Phase 1: stencil in registers; edges via shuffles ----------
    // wave wv owns channels 4wv..4wv+3; lane owns pixels 4*lane..4*lane+3.
    // Per channel: 3 coalesced float4 loads, 6 ds_bpermute shuffles, no edge
    // gathers (r5's 24 lane-divergent edge loads caused ~460B/thread scratch
    // spill -> 1GB of HBM scratch traffic). Channel PAIRS flushed immediately
    // to cap live registers at ~80.
    {
        const bool zT = (y == 0), zB = (y == 255);
        const int x4 = 4 * lane;
        const size_t rT = (size_t)(zT ? 0 : y - 1) * WDIM + x4;
        const size_t rM = (size_t)y * WDIM + x4;
        const size_t rB = (size_t)(zB ? 255 : y + 1) * WDIM + x4;
        const float* cbase = grid + (size_t)b * NC * HW + (size_t)(4 * wv) * HW;

        // one channel's stencil: vT/vM/vB in regs, edges from neighbor lanes
        #define CH_STENCIL(PC, P0, P1, P2)                                     \
        {                                                                      \
            f32x4 vT = *(const f32x4*)&(PC)[rT];                               \
            f32x4 vM = *(const f32x4*)&(PC)[rM];                               \
            f32x4 vB = *(const f32x4*)&(PC)[rB];                               \
            if (zT) { f32x4 z_ = {0,0,0,0}; vT = z_; }   /* wave-uniform */    \
            if (zB) { f32x4 z_ = {0,0,0,0}; vB = z_; }                         \
            float eTl = __shfl_up(vT[3], 1), eTr = __shfl_down(vT[0], 1);      \
            float eMl = __shfl_up(vM[3], 1), eMr = __shfl_down(vM[0], 1);      \
            float eBl = __shfl_up(vB[3], 1), eBr = __shfl_down(vB[0], 1);      \
            if (lane == 0)  { eTl = 0.f; eMl = 0.f; eBl = 0.f; }  /* x=0 */    \
            if (lane == 63) { eTr = 0.f; eMr = 0.f; eBr = 0.f; }  /* x=255 */  \
            _Pragma("unroll")                                                  \
            for (int i = 0; i < 4; ++i) {                                      \
                const float tl = i ? vT[i-1] : eTl;                            \
                const float tr = (i < 3) ? vT[i+1] : eTr;                      \
                const float ml = i ? vM[i-1] : eMl;                            \
                const float mr = (i < 3) ? vM[i+1] : eMr;                      \
                const float bl = i ? vB[i-1] : eBl;                            \
                const float br = (i < 3) ? vB[i+1] : eBr;                      \
                P0[i] = vM[i];                                                 \
                P1[i] = (tl + tr + 2.f*ml - 2.f*mr + bl - br) * 0.125f;        \
                P2[i] = (tl + 2.f*vT[i] + tr - bl - 2.f*vB[i] - br) * 0.125f;  \
            }                                                                  \
        }

        // ---- pair 0: channels 4wv+0, 4wv+1 -> shorts [12wv .. 12wv+5] ----
        {
            float a0[4], a1[4], a2[4], c0[4], c1[4], c2v[4];
            CH_STENCIL(cbase,      a0, a1, a2);
            CH_STENCIL(cbase + HW, c0, c1, c2v);
            #pragma unroll
            for (int i = 0; i < 4; ++i) {
                const int px = x4 + i;
                int2v v0 = {(int)cvt_pk(a0[i], a1[i]), (int)cvt_pk(a2[i], c0[i])};
                *spb(sP, px, 24*wv) = v0;
                *spb32(sP, px, 24*wv + 8) = (int)cvt_pk(c1[i], c2v[i]);
            }
        }
        // ---- pair 1: channels 4wv+2, 4wv+3 -> shorts [12wv+6 .. 12wv+11] ----
        {
            float a0[4], a1[4], a2[4], c0[4], c1[4], c2v[4];
            CH_STENCIL(cbase + 2*HW, a0, a1, a2);
            CH_STENCIL(cbase + 3*HW, c0, c1, c2v);
            #pragma unroll
            for (int i = 0; i < 4; ++i) {
                const int px = x4 + i;
                *spb32(sP, px, 24*wv + 12) = (int)cvt_pk(a0[i], a1[i]);
                int2v v1 = {(int)cvt_pk(a2[i], c0[i]), (int)cvt_pk(c1[i], c2v[i])};
                *spb(sP, px, 24*wv + 16) = v1;
            }
        }
        #undef CH_STENCIL
    }
    __syncthreads();   // the ONLY barrier: covers sW1F staging + all sP writes

    // ---------- Phase 3: fragments to registers ----------
    short8 w1f0[8], w1f1[8];
    #pragma unroll
    for (int n = 0; n < 8; ++n) {
        w1f0[n] = *(const short8*)&sW1F[n*768 + lane*8];
        short8 z = {}; w1f1[n] = z;
        if (lane < 32) w1f1[n] = *(const short8*)&sW1F[n*768 + 512 + lane*8];
    }
    // w2 B-frags from global (permuted o-space: o' = a*8+j' <-> o = j'*16+a, a=4t+q)
    short8 w2f[4];
    #pragma unroll
    for (int t = 0; t < 4; ++t) {
        short8 v;
        #pragma unroll
        for (int jj = 0; jj < 8; ++jj) v[jj] = f2bf(w2[l15 * NH + jj*16 + 4*t + q]);
        w2f[t] = v;
    }
    float b1v[8];
    #pragma unroll
    for (int n = 0; n < 8; ++n) b1v[n] = b1[16*n + l15];
    const float b2v = b2[l15];

    // ---------- Phase 4: MFMA MLP over this wave's 4 pixel-tiles ----------
    // prefetch A-frags for mt=1..3 (their sP rows get overlaid by H below)
    short8 aF0[3], aF1[3];
    #pragma unroll
    for (int m = 1; m < 4; ++m) {
        const int px = (wv*4 + m)*16 + l15;
        aF0[m-1] = ld_sp16(sP, px, 16*q);
        short8 a1 = {};
        if (q < 2) a1 = ld_sp16(sP, px, 64 + 16*q);   // k=32..47 real; q>=2 -> zero
        aF1[m-1] = a1;
    }
    // H overlays own-wave sP rows 16.. (4352 B needed, 4608 B available)
    short* Hb = &sP[(wv*64 + 16) * PSTR];

    #pragma unroll
    for (int mt = 0; mt < 4; ++mt) {
        short8 a0, a1;
        if (mt == 0) {       // rows 0..15 of own span are never overlaid: read JIT
            const int px = wv*64 + l15;
            a0 = ld_sp16(sP, px, 16*q);
            short8 z = {}; a1 = z;
            if (q < 2) a1 = ld_sp16(sP, px, 64 + 16*q);
        } else { a0 = aF0[mt-1]; a1 = aF1[mt-1]; }

        f32x4 acc[8];
        #pragma unroll
        for (int n = 0; n < 8; ++n) { f32x4 t4 = {b1v[n], b1v[n], b1v[n], b1v[n]}; acc[n] = t4; }
        #pragma unroll
        for (int n = 0; n < 8; ++n)
            acc[n] = __builtin_amdgcn_mfma_f32_16x16x32_bf16(a0, w1f0[n], acc[n], 0, 0, 0);
        #pragma unroll
        for (int n = 0; n < 8; ++n)
            acc[n] = __builtin_amdgcn_mfma_f32_16x16x32_bf16(a1, w1f1[n], acc[n], 0, 0, 0);

        // relu -> bf16 -> H' [m=q*4+r][o'=l15*8+n] (one b128 per r)
        #pragma unroll
        for (int rr = 0; rr < 4; ++rr) {
            unsigned h0 = cvt_pk(fmaxf(acc[0][rr], 0.f), fmaxf(acc[1][rr], 0.f));
            unsigned h1 = cvt_pk(fmaxf(acc[2][rr], 0.f), fmaxf(acc[3][rr], 0.f));
            unsigned h2 = cvt_pk(fmaxf(acc[4][rr], 0.f), fmaxf(acc[5][rr], 0.f));
            unsigned h3 = cvt_pk(fmaxf(acc[6][rr], 0.f), fmaxf(acc[7][rr], 0.f));
            int4v v = {(int)h0, (int)h1, (int)h2, (int)h3};
            *(int4v*)&Hb[(q*4 + rr) * HSTR + l15 * 8] = v;
        }
        // GEMM2: A[m=l15][k=o'=32t+8q+j] from H', B = w2f (same permutation)
        f32x4 acc2 = {b2v, b2v, b2v, b2v};
        #pragma unroll
        for (int t = 0; t < 4; ++t) {
            const short8 af = *(const short8*)&Hb[l15 * HSTR + 32*t + 8*q];
            acc2 = __builtin_amdgcn_mfma_f32_16x16x32_bf16(af, w2f[t], acc2, 0, 0, 0);
        }
        // Epilogue straight from C-layout: lane = (channel j=l15, pixels px0+4q..+3)
        const int px0 = (wv*4 + mt) * 16;
        const int px  = px0 + 4*q;
        const size_t gi = (size_t)b * NC * HW + (size_t)l15 * HW + (size_t)y * WDIM + px;
        const float4 g  = *(const float4*)&grid[gi];   // L2-hot (same XCD as phase 1)
        const float4 nz = *(const float4*)&noise[(size_t)b * HW + (size_t)y * WDIM + px];
        float4 o;
        o.x = fminf(fmaxf(g.x + acc2[0] * (nz.x < 0.5f ? 1.f : 0.f), -2.f), 2.f);
        o.y = fminf(fmaxf(g.y + acc2[1] * (nz.y < 0.5f ? 1.f : 0.f), -2.f), 2.f);
        o.z = fminf(fmaxf(g.z + acc2[2] * (nz.z < 0.5f ? 1.f : 0.f), -2.f), 2.f);
        o.w = fminf(fmaxf(g.w + acc2[3] * (nz.w < 0.5f ? 1.f : 0.f), -2.f), 2.f);
        *(float4*)&out[gi] = o;
    }
}

extern "C" void kernel_launch(void* const* d_in, const int* in_sizes, int n_in,
                              void* d_out, int out_size, void* d_ws, size_t ws_size,
                              hipStream_t stream) {
    const float* grid  = (const float*)d_in[0];
    const float* noise = (const float*)d_in[1];
    const float* w1    = (const float*)d_in[2];
    const float* b1    = (const float*)d_in[3];
    const float* w2    = (const float*)d_in[4];
    const float* b2    = (const float*)d_in[5];
    float* out = (float*)d_out;

    dim3 g(32 * 256);   // one block per (batch, row), XCD-banded inside the kernel
    nca_mfma_kernel<<<g, 256, 0, stream>>>(grid, noise, w1, b1, w2, b2, out);
}